// Round 1
// baseline (1245.410 us; speedup 1.0000x reference)
//
#include <hip/hip_runtime.h>

typedef unsigned short u16;
typedef __attribute__((ext_vector_type(8))) short bf16x8;
typedef __attribute__((ext_vector_type(4))) float f32x4;

#define GK 4096
#define GN 4096
#define BDIM 4096
#define BROWS 8192

__device__ __forceinline__ u16 f2b(float f) {
    union { float f; unsigned u; } c; c.f = f;
    unsigned u = c.u;
    return (u16)((u + 0x7FFFu + ((u >> 16) & 1u)) >> 16);
}
__device__ __forceinline__ float b2f(u16 h) {
    union { unsigned u; float f; } c; c.u = ((unsigned)h) << 16;
    return c.f;
}
__device__ __forceinline__ void gload16(const void* g, void* l) {
    __builtin_amdgcn_global_load_lds((const __attribute__((address_space(1))) void*)g,
                                     (__attribute__((address_space(3))) void*)l, 16, 0, 0);
}

// ---- convert x -> bf16 + column sums (for mean) ----
__global__ void k_cvt_colsum(const float* __restrict__ x, u16* __restrict__ xb,
                             float* __restrict__ colsum) {
    const int tid  = threadIdx.x;
    const int c4   = blockIdx.x * 64 + (tid & 63);   // float4-column 0..1023
    const int rowg = tid >> 6;                        // 0..3
    const int r0   = blockIdx.y * 128;
    const float4* x4 = (const float4*)x;
    float sx = 0.f, sy = 0.f, sz = 0.f, sw = 0.f;
    for (int i = 0; i < 32; ++i) {
        int row = r0 + i * 4 + rowg;
        float4 v = x4[(size_t)row * 1024 + c4];
        sx += v.x; sy += v.y; sz += v.z; sw += v.w;
        ushort4 o; o.x = f2b(v.x); o.y = f2b(v.y); o.z = f2b(v.z); o.w = f2b(v.w);
        *(ushort4*)(xb + (size_t)row * BDIM + c4 * 4) = o;
    }
    __shared__ float red[256][4];
    red[tid][0] = sx; red[tid][1] = sy; red[tid][2] = sz; red[tid][3] = sw;
    __syncthreads();
    if (tid < 64) {
        for (int j = 64; j < 256; j += 64) {
            sx += red[tid + j][0]; sy += red[tid + j][1];
            sz += red[tid + j][2]; sw += red[tid + j][3];
        }
        int c = blockIdx.x * 64 + tid;
        atomicAdd(&colsum[c * 4 + 0], sx);
        atomicAdd(&colsum[c * 4 + 1], sy);
        atomicAdd(&colsum[c * 4 + 2], sz);
        atomicAdd(&colsum[c * 4 + 3], sw);
    }
}

// ---- generic f32 -> bf16 convert ----
__global__ void k_cvt(const float4* __restrict__ in, ushort4* __restrict__ out, int n4) {
    int i = blockIdx.x * 256 + threadIdx.x;
    if (i >= n4) return;
    float4 v = in[i];
    ushort4 o; o.x = f2b(v.x); o.y = f2b(v.y); o.z = f2b(v.z); o.w = f2b(v.w);
    out[i] = o;
}

// ---- scalar chain -> sc[0]=crystal_osc, sc[1]=ef*0.3, sc[2]=tb*0.15 ----
__global__ void k_scalars(const float* __restrict__ colsum, const float* __restrict__ Wf,
                          const float* __restrict__ bfp, const float* __restrict__ pmem,
                          const float* __restrict__ cmom, const int* __restrict__ tstep,
                          float* __restrict__ sc) {
    const int tid = threadIdx.x;
    float s = 0.f;
    for (int i = tid; i < BDIM; i += 256) s += Wf[i] * colsum[i];
    __shared__ float red[256];
    red[tid] = s; __syncthreads();
    for (int off = 128; off > 0; off >>= 1) {
        if (tid < off) red[tid] += red[tid + off];
        __syncthreads();
    }
    if (tid == 0) {
        const float TP = 6.283185307179586f;
        float mdot = red[0] * (1.f / (float)BROWS) + bfp[0];
        float fa = 1.f / (1.f + expf(-mdot));
        int ts = tstep[0] + 1;
        float t = (float)ts / 100.f;
        float af = 1.618033f * (1.f + fa * 0.2f);
        float pp = fmodf(TP * t * af, TP);
        float sp = fmodf(pp / 1.618033f, TP);
        float co = 0.3f * (sinf(pp) + 0.3f * cosf(sp));
        float d[25];
        d[0] = pp - pmem[0];
        for (int j = 1; j < 25; ++j) d[j] = pmem[2 * j - 1] - pmem[2 * j];
        float m = 0.f;
        for (int j = 0; j < 25; ++j) m += d[j];
        m *= (1.f / 25.f);
        float var = 0.f;
        for (int j = 0; j < 25; ++j) { float e = d[j] - m; var += e * e; }
        var *= (1.f / 24.f);
        float sd = sqrtf(var);
        float pc = fminf(fmaxf(1.f - sd / TP, 0.f), 1.f);
        float cc = 0.9f * (1.f + pc * 0.2f);
        float stab = fminf((float)ts / 1000.f, 1.f);
        float coh1 = cc * (1.f + stab * 0.3f);
        float nm = 0.98f * cmom[0] + 0.02f * coh1;
        float coh = fminf(fmaxf(nm, 0.72f), 1.35f);
        float tf = 1.f + fminf((float)ts / 5000.f, 0.5f);
        sc[0] = co;
        sc[1] = coh * 1.2f * tf * 0.3f;
        sc[2] = (1.f + coh * 0.2f * tf) * 0.15f;
    }
}

// ---- cs_ef[i] = (0.98*cstate + 0.02*osc*cw*(1+tanh(Wamp@mean+bamp))) * ef*0.3 ----
__global__ void k_csef(const float* __restrict__ Wamp, const float* __restrict__ colsum,
                       const float* __restrict__ bamp, const float* __restrict__ cw,
                       const float* __restrict__ cstate, const float* __restrict__ sc,
                       float* __restrict__ csef) {
    const int row = blockIdx.x, tid = threadIdx.x;
    const float4* w4 = (const float4*)(Wamp + (size_t)row * BDIM);
    const float4* m4 = (const float4*)colsum;
    float s = 0.f;
    for (int i = tid; i < 1024; i += 256) {
        float4 w = w4[i], m = m4[i];
        s += w.x * m.x + w.y * m.y + w.z * m.z + w.w * m.w;
    }
    __shared__ float red[256];
    red[tid] = s; __syncthreads();
    for (int off = 128; off > 0; off >>= 1) {
        if (tid < off) red[tid] += red[tid + off];
        __syncthreads();
    }
    if (tid == 0) {
        float v = red[0] * (1.f / (float)BROWS) + bamp[row];
        float ew = cw[row] * (1.f + tanhf(v));
        float cs = 0.98f * cstate[row] + 0.02f * sc[0] * ew;
        csef[row] = cs * sc[1];
    }
}

// ---- bf16 NT GEMM, 128x128 tile, BK=64, fused epilogues ----
// MODE 1: enh_bf = bf16( xf + csef[col] * sigmoid(acc + bias[col]) )
// MODE 2: outf   = b2f(A[row,col]) + tanh(acc + bias[col]) * sc[2]
template <int MODE>
__global__ __launch_bounds__(256) void gemm_bt(
    const u16* __restrict__ A, const u16* __restrict__ Bm,
    const float* __restrict__ xf, const float* __restrict__ bias,
    const float* __restrict__ csef, const float* __restrict__ sc,
    u16* __restrict__ outb, float* __restrict__ outf) {
    __shared__ u16 As[128 * 64];
    __shared__ u16 Bs[128 * 64];

    const int tid = threadIdx.x;
    const int lane = tid & 63;
    const int wave = tid >> 6;
    const int waveM = wave >> 1;
    const int waveN = wave & 1;
    const int bm0 = blockIdx.y * 128;
    const int bn0 = blockIdx.x * 128;

    const u16* ag[4]; const u16* bg[4];
    u16* la[4]; u16* lb[4];
    {
        const int lr = lane >> 3;
        const int lc = (lane & 7) * 8;
#pragma unroll
        for (int i = 0; i < 4; ++i) {
            int sseg = wave * 4 + i;       // 0..15
            int r = sseg * 8 + lr;         // 0..127
            ag[i] = A + (size_t)(bm0 + r) * GK + lc;
            bg[i] = Bm + (size_t)(bn0 + r) * GK + lc;
            la[i] = &As[sseg * 512];
            lb[i] = &Bs[sseg * 512];
        }
    }

    f32x4 acc[4][4] = {};
    const int lm = lane & 15;
    const int quad = lane >> 4;
    const int arow = waveM * 64 + lm;
    const int brow = waveN * 64 + lm;

    for (int k0 = 0; k0 < GK; k0 += 64) {
#pragma unroll
        for (int i = 0; i < 4; ++i) {
            gload16(ag[i] + k0, la[i]);
            gload16(bg[i] + k0, lb[i]);
        }
        __syncthreads();
#pragma unroll
        for (int kk = 0; kk < 2; ++kk) {
            const int kb = kk * 32 + quad * 8;
            bf16x8 a[4], b[4];
#pragma unroll
            for (int mi = 0; mi < 4; ++mi)
                a[mi] = *(const bf16x8*)&As[(arow + mi * 16) * 64 + kb];
#pragma unroll
            for (int ni = 0; ni < 4; ++ni)
                b[ni] = *(const bf16x8*)&Bs[(brow + ni * 16) * 64 + kb];
#pragma unroll
            for (int mi = 0; mi < 4; ++mi)
#pragma unroll
                for (int ni = 0; ni < 4; ++ni)
                    acc[mi][ni] = __builtin_amdgcn_mfma_f32_16x16x32_bf16(
                        a[mi], b[ni], acc[mi][ni], 0, 0, 0);
        }
        __syncthreads();
    }

    const int col0 = bn0 + waveN * 64 + lm;
    const int row0 = bm0 + waveM * 64 + quad * 4;
    const float tb15 = (MODE == 2) ? sc[2] : 0.f;
#pragma unroll
    for (int mi = 0; mi < 4; ++mi) {
#pragma unroll
        for (int r = 0; r < 4; ++r) {
            const int row = row0 + mi * 16 + r;
#pragma unroll
            for (int ni = 0; ni < 4; ++ni) {
                const int col = col0 + ni * 16;
                const float v = acc[mi][ni][r];
                const size_t idx = (size_t)row * GN + col;
                if (MODE == 1) {
                    float vb = v + bias[col];
                    vb = fminf(fmaxf(vb, -30.f), 30.f);
                    float sg = 1.f / (1.f + __expf(-vb));
                    float e = xf[idx] + csef[col] * sg;
                    outb[idx] = f2b(e);
                } else {
                    float vb = v + bias[col];
                    vb = fminf(fmaxf(vb, -15.f), 15.f);
                    float e2 = __expf(2.f * vb);
                    float th = (e2 - 1.f) / (e2 + 1.f);
                    outf[idx] = b2f(A[idx]) + th * tb15;
                }
            }
        }
    }
}

extern "C" void kernel_launch(void* const* d_in, const int* in_sizes, int n_in,
                              void* d_out, int out_size, void* d_ws, size_t ws_size,
                              hipStream_t stream) {
    const float* x      = (const float*)d_in[0];
    const float* cstate = (const float*)d_in[1];
    const float* pmem   = (const float*)d_in[2];
    const float* cmom   = (const float*)d_in[3];
    const float* cw     = (const float*)d_in[4];
    const float* Wf     = (const float*)d_in[5];
    const float* bfp    = (const float*)d_in[6];
    const float* Wamp   = (const float*)d_in[7];
    const float* bamp   = (const float*)d_in[8];
    const float* Wtemp  = (const float*)d_in[9];
    const float* btemp  = (const float*)d_in[10];
    const float* Wgate  = (const float*)d_in[11];
    const float* bgate  = (const float*)d_in[12];
    const int*   tstep  = (const int*)d_in[13];
    float* out = (float*)d_out;

    char* ws = (char*)d_ws;
    u16* x_bf   = (u16*)ws;  ws += (size_t)BROWS * BDIM * 2;   // 64 MB
    u16* wg_bf  = (u16*)ws;  ws += (size_t)BDIM * BDIM * 2;    // 32 MB
    u16* wt_bf  = (u16*)ws;  ws += (size_t)BDIM * BDIM * 2;    // 32 MB
    u16* enh_bf = (u16*)ws;  ws += (size_t)BROWS * BDIM * 2;   // 64 MB
    float* colsum = (float*)ws; ws += BDIM * 4;
    float* csef   = (float*)ws; ws += BDIM * 4;
    float* sc     = (float*)ws; ws += 256;

    hipMemsetAsync(colsum, 0, BDIM * sizeof(float), stream);
    k_cvt_colsum<<<dim3(16, 64), 256, 0, stream>>>(x, x_bf, colsum);
    k_cvt<<<16384, 256, 0, stream>>>((const float4*)Wgate, (ushort4*)wg_bf, 4194304);
    k_cvt<<<16384, 256, 0, stream>>>((const float4*)Wtemp, (ushort4*)wt_bf, 4194304);
    k_scalars<<<1, 256, 0, stream>>>(colsum, Wf, bfp, pmem, cmom, tstep, sc);
    k_csef<<<4096, 256, 0, stream>>>(Wamp, colsum, bamp, cw, cstate, sc, csef);
    gemm_bt<1><<<dim3(32, 64), 256, 0, stream>>>(x_bf, wg_bf, x, bgate, csef, sc, enh_bf, nullptr);
    gemm_bt<2><<<dim3(32, 64), 256, 0, stream>>>(enh_bf, wt_bf, nullptr, btemp, nullptr, sc, nullptr, out);
}

// Round 2
// 1092.721 us; speedup vs baseline: 1.1397x; 1.1397x over previous
//
#include <hip/hip_runtime.h>

typedef unsigned short u16;
typedef __attribute__((ext_vector_type(8))) short bf16x8;
typedef __attribute__((ext_vector_type(4))) float f32x4;

#define GK 4096
#define GN 4096
#define BDIM 4096
#define BROWS 8192

__device__ __forceinline__ u16 f2b(float f) {
    union { float f; unsigned u; } c; c.f = f;
    unsigned u = c.u;
    return (u16)((u + 0x7FFFu + ((u >> 16) & 1u)) >> 16);
}
__device__ __forceinline__ float b2f(u16 h) {
    union { unsigned u; float f; } c; c.u = ((unsigned)h) << 16;
    return c.f;
}
__device__ __forceinline__ void gload16(const void* g, void* l) {
    __builtin_amdgcn_global_load_lds((const __attribute__((address_space(1))) void*)g,
                                     (__attribute__((address_space(3))) void*)l, 16, 0, 0);
}

// ---- convert x -> bf16 + column sums (for mean) ----
__global__ void k_cvt_colsum(const float* __restrict__ x, u16* __restrict__ xb,
                             float* __restrict__ colsum) {
    const int tid  = threadIdx.x;
    const int c4   = blockIdx.x * 64 + (tid & 63);   // float4-column 0..1023
    const int rowg = tid >> 6;                        // 0..3
    const int r0   = blockIdx.y * 128;
    const float4* x4 = (const float4*)x;
    float sx = 0.f, sy = 0.f, sz = 0.f, sw = 0.f;
    for (int i = 0; i < 32; ++i) {
        int row = r0 + i * 4 + rowg;
        float4 v = x4[(size_t)row * 1024 + c4];
        sx += v.x; sy += v.y; sz += v.z; sw += v.w;
        ushort4 o; o.x = f2b(v.x); o.y = f2b(v.y); o.z = f2b(v.z); o.w = f2b(v.w);
        *(ushort4*)(xb + (size_t)row * BDIM + c4 * 4) = o;
    }
    __shared__ float red[256][4];
    red[tid][0] = sx; red[tid][1] = sy; red[tid][2] = sz; red[tid][3] = sw;
    __syncthreads();
    if (tid < 64) {
        for (int j = 64; j < 256; j += 64) {
            sx += red[tid + j][0]; sy += red[tid + j][1];
            sz += red[tid + j][2]; sw += red[tid + j][3];
        }
        int c = blockIdx.x * 64 + tid;
        atomicAdd(&colsum[c * 4 + 0], sx);
        atomicAdd(&colsum[c * 4 + 1], sy);
        atomicAdd(&colsum[c * 4 + 2], sz);
        atomicAdd(&colsum[c * 4 + 3], sw);
    }
}

// ---- both weight matrices f32 -> bf16 in one launch ----
__global__ void k_cvt2(const float4* __restrict__ a, ushort4* __restrict__ ao,
                       const float4* __restrict__ b, ushort4* __restrict__ bo) {
    int i = blockIdx.x * 256 + threadIdx.x;
    const float4* in;  ushort4* out;
    if (i < 4194304) { in = a; out = ao; }
    else             { in = b; out = bo; i -= 4194304; }
    float4 v = in[i];
    ushort4 o; o.x = f2b(v.x); o.y = f2b(v.y); o.z = f2b(v.z); o.w = f2b(v.w);
    out[i] = o;
}

// ---- scalar chain -> sc[0]=crystal_osc, sc[1]=ef*0.3, sc[2]=tb*0.15 ----
__global__ void k_scalars(const float* __restrict__ colsum, const float* __restrict__ Wf,
                          const float* __restrict__ bfp, const float* __restrict__ pmem,
                          const float* __restrict__ cmom, const int* __restrict__ tstep,
                          float* __restrict__ sc) {
    const int tid = threadIdx.x;
    float s = 0.f;
    for (int i = tid; i < BDIM; i += 256) s += Wf[i] * colsum[i];
    __shared__ float red[256];
    red[tid] = s; __syncthreads();
    for (int off = 128; off > 0; off >>= 1) {
        if (tid < off) red[tid] += red[tid + off];
        __syncthreads();
    }
    if (tid == 0) {
        const float TP = 6.283185307179586f;
        float mdot = red[0] * (1.f / (float)BROWS) + bfp[0];
        float fa = 1.f / (1.f + expf(-mdot));
        int ts = tstep[0] + 1;
        float t = (float)ts / 100.f;
        float af = 1.618033f * (1.f + fa * 0.2f);
        float pp = fmodf(TP * t * af, TP);
        float sp = fmodf(pp / 1.618033f, TP);
        float co = 0.3f * (sinf(pp) + 0.3f * cosf(sp));
        float d[25];
        d[0] = pp - pmem[0];
        for (int j = 1; j < 25; ++j) d[j] = pmem[2 * j - 1] - pmem[2 * j];
        float m = 0.f;
        for (int j = 0; j < 25; ++j) m += d[j];
        m *= (1.f / 25.f);
        float var = 0.f;
        for (int j = 0; j < 25; ++j) { float e = d[j] - m; var += e * e; }
        var *= (1.f / 24.f);
        float sd = sqrtf(var);
        float pc = fminf(fmaxf(1.f - sd / TP, 0.f), 1.f);
        float cc = 0.9f * (1.f + pc * 0.2f);
        float stab = fminf((float)ts / 1000.f, 1.f);
        float coh1 = cc * (1.f + stab * 0.3f);
        float nm = 0.98f * cmom[0] + 0.02f * coh1;
        float coh = fminf(fmaxf(nm, 0.72f), 1.35f);
        float tf = 1.f + fminf((float)ts / 5000.f, 0.5f);
        sc[0] = co;
        sc[1] = coh * 1.2f * tf * 0.3f;
        sc[2] = (1.f + coh * 0.2f * tf) * 0.15f;
    }
}

// ---- cs_ef[i] = (0.98*cstate + 0.02*osc*cw*(1+tanh(Wamp@mean+bamp))) * ef*0.3 ----
__global__ void k_csef(const float* __restrict__ Wamp, const float* __restrict__ colsum,
                       const float* __restrict__ bamp, const float* __restrict__ cw,
                       const float* __restrict__ cstate, const float* __restrict__ sc,
                       float* __restrict__ csef) {
    const int row = blockIdx.x, tid = threadIdx.x;
    const float4* w4 = (const float4*)(Wamp + (size_t)row * BDIM);
    const float4* m4 = (const float4*)colsum;
    float s = 0.f;
    for (int i = tid; i < 1024; i += 256) {
        float4 w = w4[i], m = m4[i];
        s += w.x * m.x + w.y * m.y + w.z * m.z + w.w * m.w;
    }
    __shared__ float red[256];
    red[tid] = s; __syncthreads();
    for (int off = 128; off > 0; off >>= 1) {
        if (tid < off) red[tid] += red[tid + off];
        __syncthreads();
    }
    if (tid == 0) {
        float v = red[0] * (1.f / (float)BROWS) + bamp[row];
        float ew = cw[row] * (1.f + tanhf(v));
        float cs = 0.98f * cstate[row] + 0.02f * sc[0] * ew;
        csef[row] = cs * sc[1];
    }
}

// ---- bf16 NT GEMM, 128x128 tile, BK=64, XOR-swizzled LDS, fused epilogues ----
// LDS layout: tile row r, physical 16B chunk p holds global chunk (p ^ (r&7)).
// Staging: lane (lr=lane>>3, lc=lane&7) fetches global chunk (lc^lr) of row lr;
// HW writes it to base+lane*16 = physical chunk lc.  [kills 16-way bank conflicts]
// MODE 1: enh_bf = bf16( xf + csef[col] * sigmoid(acc + bias[col]) )
// MODE 2: outf   = b2f(A[row,col]) + tanh(acc + bias[col]) * sc[2]
template <int MODE>
__global__ __launch_bounds__(256) void gemm_bt(
    const u16* __restrict__ A, const u16* __restrict__ Bm,
    const float* __restrict__ xf, const float* __restrict__ bias,
    const float* __restrict__ csef, const float* __restrict__ sc,
    u16* __restrict__ outb, float* __restrict__ outf) {
    __shared__ u16 As[128 * 64];
    __shared__ u16 Bs[128 * 64];

    const int tid = threadIdx.x;
    const int lane = tid & 63;
    const int wave = tid >> 6;
    const int waveM = wave >> 1;
    const int waveN = wave & 1;
    const int bm0 = blockIdx.y * 128;
    const int bn0 = blockIdx.x * 128;

    const u16* ag[4]; const u16* bg[4];
    u16* la[4]; u16* lb[4];
    {
        const int lr = lane >> 3;
        const int lc = lane & 7;
        const int gcol = (lc ^ lr) * 8;          // swizzled global chunk
#pragma unroll
        for (int i = 0; i < 4; ++i) {
            int sseg = wave * 4 + i;             // 0..15
            int r = sseg * 8 + lr;               // 0..127
            ag[i] = A + (size_t)(bm0 + r) * GK + gcol;
            bg[i] = Bm + (size_t)(bn0 + r) * GK + gcol;
            la[i] = &As[sseg * 512];
            lb[i] = &Bs[sseg * 512];
        }
    }

    f32x4 acc[4][4] = {};
    const int lm = lane & 15;
    const int quad = lane >> 4;
    const int arow = waveM * 64 + lm;
    const int brow = waveN * 64 + lm;
    const int rsw = lm & 7;                      // row&7 for all fragment rows

    for (int k0 = 0; k0 < GK; k0 += 64) {
#pragma unroll
        for (int i = 0; i < 4; ++i) {
            gload16(ag[i] + k0, la[i]);
            gload16(bg[i] + k0, lb[i]);
        }
        __syncthreads();
#pragma unroll
        for (int kk = 0; kk < 2; ++kk) {
            const int pch = ((kk * 4 + quad) ^ rsw) * 8;   // de-swizzled chunk
            bf16x8 a[4], b[4];
#pragma unroll
            for (int mi = 0; mi < 4; ++mi)
                a[mi] = *(const bf16x8*)&As[(arow + mi * 16) * 64 + pch];
#pragma unroll
            for (int ni = 0; ni < 4; ++ni)
                b[ni] = *(const bf16x8*)&Bs[(brow + ni * 16) * 64 + pch];
#pragma unroll
            for (int mi = 0; mi < 4; ++mi)
#pragma unroll
                for (int ni = 0; ni < 4; ++ni)
                    acc[mi][ni] = __builtin_amdgcn_mfma_f32_16x16x32_bf16(
                        a[mi], b[ni], acc[mi][ni], 0, 0, 0);
        }
        __syncthreads();
    }

    const int col0 = bn0 + waveN * 64 + lm;
    const int row0 = bm0 + waveM * 64 + quad * 4;
    const float tb15 = (MODE == 2) ? sc[2] : 0.f;
#pragma unroll
    for (int mi = 0; mi < 4; ++mi) {
#pragma unroll
        for (int r = 0; r < 4; ++r) {
            const int row = row0 + mi * 16 + r;
#pragma unroll
            for (int ni = 0; ni < 4; ++ni) {
                const int col = col0 + ni * 16;
                const float v = acc[mi][ni][r];
                const size_t idx = (size_t)row * GN + col;
                if (MODE == 1) {
                    float vb = v + bias[col];
                    vb = fminf(fmaxf(vb, -30.f), 30.f);
                    float sg = 1.f / (1.f + __expf(-vb));
                    float e = xf[idx] + csef[col] * sg;
                    outb[idx] = f2b(e);
                } else {
                    float vb = v + bias[col];
                    vb = fminf(fmaxf(vb, -15.f), 15.f);
                    float e2 = __expf(2.f * vb);
                    float th = (e2 - 1.f) / (e2 + 1.f);
                    outf[idx] = b2f(A[idx]) + th * tb15;
                }
            }
        }
    }
}

extern "C" void kernel_launch(void* const* d_in, const int* in_sizes, int n_in,
                              void* d_out, int out_size, void* d_ws, size_t ws_size,
                              hipStream_t stream) {
    const float* x      = (const float*)d_in[0];
    const float* cstate = (const float*)d_in[1];
    const float* pmem   = (const float*)d_in[2];
    const float* cmom   = (const float*)d_in[3];
    const float* cw     = (const float*)d_in[4];
    const float* Wf     = (const float*)d_in[5];
    const float* bfp    = (const float*)d_in[6];
    const float* Wamp   = (const float*)d_in[7];
    const float* bamp   = (const float*)d_in[8];
    const float* Wtemp  = (const float*)d_in[9];
    const float* btemp  = (const float*)d_in[10];
    const float* Wgate  = (const float*)d_in[11];
    const float* bgate  = (const float*)d_in[12];
    const int*   tstep  = (const int*)d_in[13];
    float* out = (float*)d_out;

    char* ws = (char*)d_ws;
    u16* x_bf   = (u16*)ws;  ws += (size_t)BROWS * BDIM * 2;   // 64 MB
    u16* wg_bf  = (u16*)ws;  ws += (size_t)BDIM * BDIM * 2;    // 32 MB
    u16* wt_bf  = (u16*)ws;  ws += (size_t)BDIM * BDIM * 2;    // 32 MB
    u16* enh_bf = (u16*)ws;  ws += (size_t)BROWS * BDIM * 2;   // 64 MB
    float* colsum = (float*)ws; ws += BDIM * 4;
    float* csef   = (float*)ws; ws += BDIM * 4;
    float* sc     = (float*)ws; ws += 256;

    hipMemsetAsync(colsum, 0, BDIM * sizeof(float), stream);
    k_cvt_colsum<<<dim3(16, 64), 256, 0, stream>>>(x, x_bf, colsum);
    k_cvt2<<<32768, 256, 0, stream>>>((const float4*)Wgate, (ushort4*)wg_bf,
                                      (const float4*)Wtemp, (ushort4*)wt_bf);
    k_scalars<<<1, 256, 0, stream>>>(colsum, Wf, bfp, pmem, cmom, tstep, sc);
    k_csef<<<4096, 256, 0, stream>>>(Wamp, colsum, bamp, cw, cstate, sc, csef);
    gemm_bt<1><<<dim3(32, 64), 256, 0, stream>>>(x_bf, wg_bf, x, bgate, csef, sc, enh_bf, nullptr);
    gemm_bt<2><<<dim3(32, 64), 256, 0, stream>>>(enh_bf, wt_bf, nullptr, btemp, nullptr, sc, nullptr, out);
}